// Round 7
// baseline (636.471 us; speedup 1.0000x reference)
//
#include <hip/hip_runtime.h>
#include <hip/hip_bf16.h>
#include <stdint.h>

#define B_ 128
#define T_ 255
#define N_ 256
#define H_ 256

// k4 k-split layout (round-1 proven): thread (kh, n2) owns columns n2 and
// n2+512, k-pairs [kh*64, kh*64+64). 48 pairs/col in registers, 16 pairs/col
// in LDS (8 planes x 1024 cols x uint4 = 128 KB).
// Round-7 change: h is fetched with ONE per-lane ds_read_b128 per wave per
// step (lane l gets 16B chunk l&15 of the wave's k-half) and distributed
// in-register via readlane -> SGPR operands for fdot2. Replaces 16 uniform
// LDS broadcast reads/wave (the dominant LDS op class, 256 ops/CU/step)
// with VALU readlanes on a 29%-busy VALU pipe.
#define RP2 48
#define LG2 4

typedef _Float16 f16;
typedef _Float16 f16x2 __attribute__((ext_vector_type(2)));
typedef _Float16 f16x8 __attribute__((ext_vector_type(8)));
typedef float f32x4 __attribute__((ext_vector_type(4)));

static __device__ __forceinline__ float fdot2(uint32_t h, uint32_t u, float acc) {
#if __has_builtin(__builtin_amdgcn_fdot2)
  return __builtin_amdgcn_fdot2(__builtin_bit_cast(f16x2, h),
                                __builtin_bit_cast(f16x2, u), acc, false);
#else
  f16x2 a = __builtin_bit_cast(f16x2, h);
  f16x2 b = __builtin_bit_cast(f16x2, u);
  return acc + (float)a.x * (float)b.x + (float)a.y * (float)b.y;
#endif
}

// ---------------- K0: pack W_lstm (transposed) and U_lstm (k-pair packed) to f16
__global__ __launch_bounds__(256) void k0_pack(const float* __restrict__ Wl,
                                               const float* __restrict__ Ul,
                                               uint32_t* __restrict__ u_packed,
                                               f16* __restrict__ wt) {
  int idx = blockIdx.x * 256 + threadIdx.x;
  if (idx < 256 * 1024) {              // wt[n][k] = Wl[k][n]
    int n = idx >> 8, k = idx & 255;
    wt[n * 256 + k] = (f16)Wl[k * 1024 + n];
  }
  if (idx < 128 * 1024) {              // u_packed[p][c] = (U[2p][c], U[2p+1][c])
    int p = idx >> 10, c = idx & 1023;
    f16x2 v;
    v.x = (f16)Ul[(2 * p) * 1024 + c];
    v.y = (f16)Ul[(2 * p + 1) * 1024 + c];
    u_packed[idx] = __builtin_bit_cast(uint32_t, v);
  }
}

// ---------------- K1: alpha[b][n] = softmax_n( sum_t X[b,t,n] * Wa[512+t] )
__global__ __launch_bounds__(256) void k1_alpha(const float* __restrict__ X,
                                                const float* __restrict__ Wa,
                                                float* __restrict__ alpha) {
  int b = blockIdx.x, n = threadIdx.x;
  const float* xb = X + b * (T_ * N_) + n;
  float a0 = 0.f, a1 = 0.f, a2 = 0.f, a3 = 0.f;
  int t = 0;
  for (; t + 4 <= T_; t += 4) {
    a0 += xb[(t + 0) * N_] * Wa[512 + t + 0];
    a1 += xb[(t + 1) * N_] * Wa[512 + t + 1];
    a2 += xb[(t + 2) * N_] * Wa[512 + t + 2];
    a3 += xb[(t + 3) * N_] * Wa[512 + t + 3];
  }
  for (; t < T_; ++t) a0 += xb[t * N_] * Wa[512 + t];
  float e = (a0 + a1) + (a2 + a3);

  __shared__ float red[4];
  float m = e;
  for (int off = 32; off > 0; off >>= 1) m = fmaxf(m, __shfl_xor(m, off));
  int wid = n >> 6;
  if ((n & 63) == 0) red[wid] = m;
  __syncthreads();
  m = fmaxf(fmaxf(red[0], red[1]), fmaxf(red[2], red[3]));
  float ex = __expf(e - m);
  float s = ex;
  for (int off = 32; off > 0; off >>= 1) s += __shfl_xor(s, off);
  __syncthreads();
  if ((n & 63) == 0) red[wid] = s;
  __syncthreads();
  s = (red[0] + red[1]) + (red[2] + red[3]);
  alpha[b * N_ + n] = ex / s;
}

// ---------------- K2: X_tilde = alpha (broadcast over t) * X   (exact fp32)
__global__ __launch_bounds__(256) void k2_xtilde(const float4* __restrict__ X4,
                                                 const float* __restrict__ alpha,
                                                 float4* __restrict__ out4) {
  int i = blockIdx.x * 256 + threadIdx.x;  // over B*T*64 float4s
  if (i < B_ * T_ * 64) {
    int n4 = i & 63;
    int bt = i >> 6;
    int b = bt / T_;
    const float4* A4 = (const float4*)alpha;
    float4 x = X4[i], al = A4[b * 64 + n4];
    float4 r;
    r.x = x.x * al.x; r.y = x.y * al.y; r.z = x.z * al.z; r.w = x.w * al.w;
    out4[i] = r;
  }
}

// ---------------- K3: XW = (alpha .* X) @ W_lstm + b_lstm  -> f16 (32640 x 1024)
// ALPHA-FUSED: reads X directly and applies alpha[b][k] during the A->f16
// pack (same fp32 multiply then f16 convert as the k2 path => identical xw).
#define LDA 40  // f16 row stride in LDS (16B-aligned rows, bank-spread)
__global__ __launch_bounds__(256, 2) void k3_gemm(const float* __restrict__ Xg,
                                                  const float* __restrict__ alpha,
                                                  const f16* __restrict__ Bt,
                                                  const float* __restrict__ bias,
                                                  f16* __restrict__ Cw) {
  __shared__ f16 As[128 * LDA];
  __shared__ f16 Bs[128 * LDA];
  int tid = threadIdx.x;
  int mt = blockIdx.x;  // 0..254
  int nt = blockIdx.y;  // 0..7
  int lane = tid & 63, wid = tid >> 6;
  int wm = (wid >> 1) * 64, wn = (wid & 1) * 64;
  int b0 = (mt * 128) / T_;          // tile spans at most one batch boundary
  int bnd = (b0 + 1) * T_;
  f32x4 acc[4][4] = {};

  for (int k0 = 0; k0 < 256; k0 += 32) {
    __syncthreads();
#pragma unroll
    for (int it = 0; it < 4; ++it) {  // A: 128 rows x 32 (alpha*X) -> f16
      int idx = tid + it * 256;
      int r = idx >> 3, q = idx & 7;
      int row = mt * 128 + r;
      int b = (row >= bnd) ? (b0 + 1) : b0;
      float4 v = *(const float4*)(Xg + row * 256 + k0 + q * 4);
      float4 al = *(const float4*)(alpha + b * 256 + k0 + q * 4);
      v.x *= al.x; v.y *= al.y; v.z *= al.z; v.w *= al.w;
      f16x2 p0, p1;
      p0.x = (f16)v.x; p0.y = (f16)v.y; p1.x = (f16)v.z; p1.y = (f16)v.w;
      uint2 w;
      w.x = __builtin_bit_cast(uint32_t, p0);
      w.y = __builtin_bit_cast(uint32_t, p1);
      *(uint2*)(&As[r * LDA + q * 4]) = w;
    }
#pragma unroll
    for (int it = 0; it < 2; ++it) {  // B (already transposed): 128 rows x 32 f16
      int idx = tid + it * 256;
      int r = idx >> 2, q = idx & 3;
      uint4 v = *(const uint4*)(Bt + (nt * 128 + r) * 256 + k0 + q * 8);
      *(uint4*)(&Bs[r * LDA + q * 8]) = v;
    }
    __syncthreads();
    int kb = (lane >> 4) * 8;
    f16x8 af[4], bf[4];
#pragma unroll
    for (int i = 0; i < 4; ++i)
      af[i] = *(const f16x8*)(&As[(wm + i * 16 + (lane & 15)) * LDA + kb]);
#pragma unroll
    for (int j = 0; j < 4; ++j)
      bf[j] = *(const f16x8*)(&Bs[(wn + j * 16 + (lane & 15)) * LDA + kb]);
#pragma unroll
    for (int i = 0; i < 4; ++i)
#pragma unroll
      for (int j = 0; j < 4; ++j)
        acc[i][j] = __builtin_amdgcn_mfma_f32_16x16x32_f16(af[i], bf[j], acc[i][j], 0, 0, 0);
  }
  int colL = wn + (lane & 15);
  int rowB = wm + (lane >> 4) * 4;
#pragma unroll
  for (int j = 0; j < 4; ++j) {
    int ng = nt * 128 + colL + j * 16;
    float bv = bias[ng];
#pragma unroll
    for (int i = 0; i < 4; ++i)
#pragma unroll
      for (int r = 0; r < 4; ++r) {
        int mg = mt * 128 + rowB + i * 16 + r;
        Cw[mg * 1024 + ng] = (f16)(acc[i][j][r] + bv);
      }
  }
}

// ---------------- K4: sequential LSTM recurrence, one block per batch.
// Round-5 structure, h-broadcast via readlane:
//  - dot phase fetches h with ONE per-lane ds_read_b128 (lane l reads the
//    16B chunk (l&15) of this wave's k-half; 4x duplicated across the wave,
//    2-way bank alias = free);
//  - chunk g is then broadcast with 4x readlane(., g) -> wave-uniform SGPRs
//    feeding fdot2's single-SGPR operand slot.
// LDS wave-ops/CU/step drop 384 -> ~190; readlanes land on the ~29%-busy
// VALU pipe.
__global__ __launch_bounds__(1024) void k4_recur(const float* __restrict__ X,
                                                 const uint32_t* __restrict__ u_packed,
                                                 const f16* __restrict__ xwf,
                                                 float* __restrict__ Xenc) {
  __shared__ __align__(16) uint32_t u_lds[8 * 1024 * 4];  // 128 KB
  __shared__ __align__(16) f16 h_lds[256];                // 512 B
  __shared__ __align__(16) float z_lds[2048];             // 8 KB ([kh][col])
  int tid = threadIdx.x, b = blockIdx.x;
  int kh = tid >> 9, n2 = tid & 511;
  int lane = tid & 63;

  // register part: pairs [kh*64, kh*64+RP2) for cols n2 and n2+512
  uint32_t urA[RP2], urB[RP2];
  int pbase = kh * 64;
#pragma unroll
  for (int p = 0; p < RP2; ++p) {
    urA[p] = u_packed[(pbase + p) * 1024 + n2];
    urB[p] = u_packed[(pbase + p) * 1024 + n2 + 512];
  }
  // LDS part: plane pl = g*2 + kh2 holds pairs (kh2*64 + RP2 + 4g .. +3)
  // for all 1024 cols, uint4-interleaved.
  {
    uint4* dst = (uint4*)u_lds;
#pragma unroll
    for (int pl = 0; pl < 2 * LG2; ++pl) {
      int kh2 = pl & 1, g = pl >> 1;
      int bp = kh2 * 64 + RP2 + 4 * g;
      uint4 v;
      v.x = u_packed[(bp + 0) * 1024 + tid];
      v.y = u_packed[(bp + 1) * 1024 + tid];
      v.z = u_packed[(bp + 2) * 1024 + tid];
      v.w = u_packed[(bp + 3) * 1024 + tid];
      dst[pl * 1024 + tid] = v;
    }
  }
  float x00 = X[b * (T_ * N_)];
  float c_st = x00;
  if (tid < 256) h_lds[tid] = (f16)x00;
  __syncthreads();

  const f16* xwb = xwf + (size_t)b * T_ * 1024;
  float* encb = Xenc + (size_t)b * T_ * N_;
  const uint4* h4 = (const uint4*)h_lds;   // 16 chunks of 16B per k-half
  const uint4* u4 = (const uint4*)u_lds;

  // each thread prefetches xw for its "own" column (== tid), coalesced
  float xwv = (float)xwb[tid];
  for (int t = 0; t < T_; ++t) {
    float xw_nxt = 0.f;
    if (t + 1 < T_) xw_nxt = (float)xwb[(t + 1) * 1024 + tid];

    // ONE LDS h-fetch per wave: lane l holds chunk (l&15) of this k-half.
    uint4 hv = h4[kh * 16 + (lane & 15)];

    float zA0 = (kh == 0) ? xwv : 0.f, zA1 = 0.f;  // col n2
    float zB0 = (kh == 0) ? 0.f : xwv, zB1 = 0.f;  // col n2+512
#pragma unroll
    for (int g = 0; g < 12; ++g) {  // register part: chunk g = pairs 4g..4g+3
      uint32_t h0 = (uint32_t)__builtin_amdgcn_readlane((int)hv.x, g);
      uint32_t h1 = (uint32_t)__builtin_amdgcn_readlane((int)hv.y, g);
      uint32_t h2 = (uint32_t)__builtin_amdgcn_readlane((int)hv.z, g);
      uint32_t h3 = (uint32_t)__builtin_amdgcn_readlane((int)hv.w, g);
      zA0 = fdot2(h0, urA[4 * g + 0], zA0);
      zA1 = fdot2(h1, urA[4 * g + 1], zA1);
      zA0 = fdot2(h2, urA[4 * g + 2], zA0);
      zA1 = fdot2(h3, urA[4 * g + 3], zA1);
      zB0 = fdot2(h0, urB[4 * g + 0], zB0);
      zB1 = fdot2(h1, urB[4 * g + 1], zB1);
      zB0 = fdot2(h2, urB[4 * g + 2], zB0);
      zB1 = fdot2(h3, urB[4 * g + 3], zB1);
    }
#pragma unroll
    for (int j = 0; j < LG2; ++j) {  // LDS-u part: chunk 12+j = pairs 48+4j..
      int g = 12 + j;
      uint32_t h0 = (uint32_t)__builtin_amdgcn_readlane((int)hv.x, g);
      uint32_t h1 = (uint32_t)__builtin_amdgcn_readlane((int)hv.y, g);
      uint32_t h2 = (uint32_t)__builtin_amdgcn_readlane((int)hv.z, g);
      uint32_t h3 = (uint32_t)__builtin_amdgcn_readlane((int)hv.w, g);
      uint4 uA = u4[(j * 2 + kh) * 1024 + n2];
      uint4 uB = u4[(j * 2 + kh) * 1024 + n2 + 512];
      zA0 = fdot2(h0, uA.x, zA0);
      zA1 = fdot2(h1, uA.y, zA1);
      zA0 = fdot2(h2, uA.z, zA0);
      zA1 = fdot2(h3, uA.w, zA1);
      zB0 = fdot2(h0, uB.x, zB0);
      zB1 = fdot2(h1, uB.y, zB1);
      zB0 = fdot2(h2, uB.z, zB0);
      zB1 = fdot2(h3, uB.w, zB1);
    }
    z_lds[kh * 1024 + n2] = zA0 + zA1;
    z_lds[kh * 1024 + n2 + 512] = zB0 + zB1;
    __syncthreads();
    if (tid < 256) {
      float zi = z_lds[tid] + z_lds[1024 + tid];
      float zf = z_lds[256 + tid] + z_lds[1280 + tid];
      float zg = z_lds[512 + tid] + z_lds[1536 + tid];
      float zo = z_lds[768 + tid] + z_lds[1792 + tid];
      float ig = 1.f / (1.f + __expf(-zi));
      float fg = 1.f / (1.f + __expf(-zf));
      float gg = 1.f - 2.f / (1.f + __expf(2.f * zg));
      float og = 1.f / (1.f + __expf(-zo));
      c_st = fg * c_st + ig * gg;
      float hv2 = og * (1.f - 2.f / (1.f + __expf(2.f * c_st)));
      encb[t * 256 + tid] = hv2;
      h_lds[tid] = (f16)hv2;
    }
    __syncthreads();
    xwv = xw_nxt;
  }
}

extern "C" void kernel_launch(void* const* d_in, const int* in_sizes, int n_in,
                              void* d_out, int out_size, void* d_ws, size_t ws_size,
                              hipStream_t stream) {
  const float* X = (const float*)d_in[0];
  const float* Wa = (const float*)d_in[1];
  const float* Wl = (const float*)d_in[3];
  const float* Ul = (const float*)d_in[4];
  const float* bl = (const float*)d_in[5];
  float* out = (float*)d_out;
  uint8_t* ws = (uint8_t*)d_ws;

  float* alpha = (float*)ws;                          // 131072 B
  uint32_t* u_packed = (uint32_t*)(ws + 131072);      // 524288 B
  f16* wt = (f16*)(ws + 655360);                      // 524288 B
  f16* xw = (f16*)(ws + 1179648);                     // 66846720 B (~68 MB total)

  k0_pack<<<1024, 256, 0, stream>>>(Wl, Ul, u_packed, wt);
  k1_alpha<<<128, 256, 0, stream>>>(X, Wa, alpha);
  k2_xtilde<<<8160, 256, 0, stream>>>((const float4*)X, alpha, (float4*)out);
  dim3 g3(255, 8);
  k3_gemm<<<g3, 256, 0, stream>>>(X, alpha, wt, bl, xw);
  k4_recur<<<128, 1024, 0, stream>>>(X, u_packed, xw, out + 8355840);
}

// Round 8
// 541.375 us; speedup vs baseline: 1.1757x; 1.1757x over previous
//
#include <hip/hip_runtime.h>
#include <hip/hip_bf16.h>
#include <stdint.h>

#define B_ 128
#define T_ 255
#define N_ 256
#define H_ 256

// k4 k-split layout (round-1 proven, round-5 tuned): thread (kh, n2) owns
// columns n2 and n2+512, k-pairs [kh*64, kh*64+64). 48 pairs/col in
// registers (96 regs, AGPR-resident), 16 pairs/col in LDS (8 planes x 1024
// cols x uint4 = 128 KB). u-LDS reads interleaved into the register-fdot2
// loop (round-5, best measured: 486us). Plain __syncthreads (round-6's
// LDS-only barrier was neutral-to-worse; round-7's readlane h-broadcast
// and round-4's quad-split both regressed -- LDS broadcasts are cheaper
// than the VALU ops needed to avoid them on this step).
#define RP2 48
#define LG2 4

typedef _Float16 f16;
typedef _Float16 f16x2 __attribute__((ext_vector_type(2)));
typedef _Float16 f16x8 __attribute__((ext_vector_type(8)));
typedef float f32x4 __attribute__((ext_vector_type(4)));

static __device__ __forceinline__ float fdot2(uint32_t h, uint32_t u, float acc) {
#if __has_builtin(__builtin_amdgcn_fdot2)
  return __builtin_amdgcn_fdot2(__builtin_bit_cast(f16x2, h),
                                __builtin_bit_cast(f16x2, u), acc, false);
#else
  f16x2 a = __builtin_bit_cast(f16x2, h);
  f16x2 b = __builtin_bit_cast(f16x2, u);
  return acc + (float)a.x * (float)b.x + (float)a.y * (float)b.y;
#endif
}

// ---------------- K0: pack W_lstm (transposed) and U_lstm (k-pair packed) to f16
__global__ __launch_bounds__(256) void k0_pack(const float* __restrict__ Wl,
                                               const float* __restrict__ Ul,
                                               uint32_t* __restrict__ u_packed,
                                               f16* __restrict__ wt) {
  int idx = blockIdx.x * 256 + threadIdx.x;
  if (idx < 256 * 1024) {              // wt[n][k] = Wl[k][n]
    int n = idx >> 8, k = idx & 255;
    wt[n * 256 + k] = (f16)Wl[k * 1024 + n];
  }
  if (idx < 128 * 1024) {              // u_packed[p][c] = (U[2p][c], U[2p+1][c])
    int p = idx >> 10, c = idx & 1023;
    f16x2 v;
    v.x = (f16)Ul[(2 * p) * 1024 + c];
    v.y = (f16)Ul[(2 * p + 1) * 1024 + c];
    u_packed[idx] = __builtin_bit_cast(uint32_t, v);
  }
}

// ---------------- K1: alpha[b][n] = softmax_n( sum_t X[b,t,n] * Wa[512+t] )
__global__ __launch_bounds__(256) void k1_alpha(const float* __restrict__ X,
                                                const float* __restrict__ Wa,
                                                float* __restrict__ alpha) {
  int b = blockIdx.x, n = threadIdx.x;
  const float* xb = X + b * (T_ * N_) + n;
  float a0 = 0.f, a1 = 0.f, a2 = 0.f, a3 = 0.f;
  int t = 0;
  for (; t + 4 <= T_; t += 4) {
    a0 += xb[(t + 0) * N_] * Wa[512 + t + 0];
    a1 += xb[(t + 1) * N_] * Wa[512 + t + 1];
    a2 += xb[(t + 2) * N_] * Wa[512 + t + 2];
    a3 += xb[(t + 3) * N_] * Wa[512 + t + 3];
  }
  for (; t < T_; ++t) a0 += xb[t * N_] * Wa[512 + t];
  float e = (a0 + a1) + (a2 + a3);

  __shared__ float red[4];
  float m = e;
  for (int off = 32; off > 0; off >>= 1) m = fmaxf(m, __shfl_xor(m, off));
  int wid = n >> 6;
  if ((n & 63) == 0) red[wid] = m;
  __syncthreads();
  m = fmaxf(fmaxf(red[0], red[1]), fmaxf(red[2], red[3]));
  float ex = __expf(e - m);
  float s = ex;
  for (int off = 32; off > 0; off >>= 1) s += __shfl_xor(s, off);
  __syncthreads();
  if ((n & 63) == 0) red[wid] = s;
  __syncthreads();
  s = (red[0] + red[1]) + (red[2] + red[3]);
  alpha[b * N_ + n] = ex / s;
}

// ---------------- K2: X_tilde = alpha (broadcast over t) * X   (exact fp32)
__global__ __launch_bounds__(256) void k2_xtilde(const float4* __restrict__ X4,
                                                 const float* __restrict__ alpha,
                                                 float4* __restrict__ out4) {
  int i = blockIdx.x * 256 + threadIdx.x;  // over B*T*64 float4s
  if (i < B_ * T_ * 64) {
    int n4 = i & 63;
    int bt = i >> 6;
    int b = bt / T_;
    const float4* A4 = (const float4*)alpha;
    float4 x = X4[i], al = A4[b * 64 + n4];
    float4 r;
    r.x = x.x * al.x; r.y = x.y * al.y; r.z = x.z * al.z; r.w = x.w * al.w;
    out4[i] = r;
  }
}

// ---------------- K3: XW = X_tilde @ W_lstm + b_lstm  -> f16 (32640 x 1024)
// UNFUSED (round-1 form): reads the x_tilde k2 just wrote (L2/L3-hot).
// The round-5 alpha-fused variant cost ~9us extra in the staging loop.
#define LDA 40  // f16 row stride in LDS (16B-aligned rows, bank-spread)
__global__ __launch_bounds__(256, 2) void k3_gemm(const float* __restrict__ A,
                                                  const f16* __restrict__ Bt,
                                                  const float* __restrict__ bias,
                                                  f16* __restrict__ Cw) {
  __shared__ f16 As[128 * LDA];
  __shared__ f16 Bs[128 * LDA];
  int tid = threadIdx.x;
  int mt = blockIdx.x;  // 0..254
  int nt = blockIdx.y;  // 0..7
  int lane = tid & 63, wid = tid >> 6;
  int wm = (wid >> 1) * 64, wn = (wid & 1) * 64;
  f32x4 acc[4][4] = {};

  for (int k0 = 0; k0 < 256; k0 += 32) {
    __syncthreads();
#pragma unroll
    for (int it = 0; it < 4; ++it) {  // A: 128 rows x 32 f32 -> f16
      int idx = tid + it * 256;
      int r = idx >> 3, q = idx & 7;
      float4 v = *(const float4*)(A + (mt * 128 + r) * 256 + k0 + q * 4);
      f16x2 p0, p1;
      p0.x = (f16)v.x; p0.y = (f16)v.y; p1.x = (f16)v.z; p1.y = (f16)v.w;
      uint2 w;
      w.x = __builtin_bit_cast(uint32_t, p0);
      w.y = __builtin_bit_cast(uint32_t, p1);
      *(uint2*)(&As[r * LDA + q * 4]) = w;
    }
#pragma unroll
    for (int it = 0; it < 2; ++it) {  // B (already transposed): 128 rows x 32 f16
      int idx = tid + it * 256;
      int r = idx >> 2, q = idx & 3;
      uint4 v = *(const uint4*)(Bt + (nt * 128 + r) * 256 + k0 + q * 8);
      *(uint4*)(&Bs[r * LDA + q * 8]) = v;
    }
    __syncthreads();
    int kb = (lane >> 4) * 8;
    f16x8 af[4], bf[4];
#pragma unroll
    for (int i = 0; i < 4; ++i)
      af[i] = *(const f16x8*)(&As[(wm + i * 16 + (lane & 15)) * LDA + kb]);
#pragma unroll
    for (int j = 0; j < 4; ++j)
      bf[j] = *(const f16x8*)(&Bs[(wn + j * 16 + (lane & 15)) * LDA + kb]);
#pragma unroll
    for (int i = 0; i < 4; ++i)
#pragma unroll
      for (int j = 0; j < 4; ++j)
        acc[i][j] = __builtin_amdgcn_mfma_f32_16x16x32_f16(af[i], bf[j], acc[i][j], 0, 0, 0);
  }
  int colL = wn + (lane & 15);
  int rowB = wm + (lane >> 4) * 4;
#pragma unroll
  for (int j = 0; j < 4; ++j) {
    int ng = nt * 128 + colL + j * 16;
    float bv = bias[ng];
#pragma unroll
    for (int i = 0; i < 4; ++i)
#pragma unroll
      for (int r = 0; r < 4; ++r) {
        int mg = mt * 128 + rowB + i * 16 + r;
        Cw[mg * 1024 + ng] = (f16)(acc[i][j][r] + bv);
      }
  }
}

// ---------------- K4: sequential LSTM recurrence, one block per batch.
// Round-5 version verbatim (best measured: 486us).
__global__ __launch_bounds__(1024) void k4_recur(const float* __restrict__ X,
                                                 const uint32_t* __restrict__ u_packed,
                                                 const f16* __restrict__ xwf,
                                                 float* __restrict__ Xenc) {
  __shared__ __align__(16) uint32_t u_lds[8 * 1024 * 4];  // 128 KB
  __shared__ __align__(16) f16 h_lds[256];                // 512 B
  __shared__ __align__(16) float z_lds[2048];             // 8 KB ([kh][col])
  int tid = threadIdx.x, b = blockIdx.x;
  int kh = tid >> 9, n2 = tid & 511;

  // register part: pairs [kh*64, kh*64+RP2) for cols n2 and n2+512
  uint32_t urA[RP2], urB[RP2];
  int pbase = kh * 64;
#pragma unroll
  for (int p = 0; p < RP2; ++p) {
    urA[p] = u_packed[(pbase + p) * 1024 + n2];
    urB[p] = u_packed[(pbase + p) * 1024 + n2 + 512];
  }
  // LDS part: plane pl = g*2 + kh2 holds pairs (kh2*64 + RP2 + 4g .. +3)
  // for all 1024 cols, uint4-interleaved.
  {
    uint4* dst = (uint4*)u_lds;
#pragma unroll
    for (int pl = 0; pl < 2 * LG2; ++pl) {
      int kh2 = pl & 1, g = pl >> 1;
      int bp = kh2 * 64 + RP2 + 4 * g;
      uint4 v;
      v.x = u_packed[(bp + 0) * 1024 + tid];
      v.y = u_packed[(bp + 1) * 1024 + tid];
      v.z = u_packed[(bp + 2) * 1024 + tid];
      v.w = u_packed[(bp + 3) * 1024 + tid];
      dst[pl * 1024 + tid] = v;
    }
  }
  float x00 = X[b * (T_ * N_)];
  float c_st = x00;
  if (tid < 256) h_lds[tid] = (f16)x00;
  __syncthreads();

  const f16* xwb = xwf + (size_t)b * T_ * 1024;
  float* encb = Xenc + (size_t)b * T_ * N_;
  const uint4* h4 = (const uint4*)h_lds;
  const uint4* u4 = (const uint4*)u_lds;

  // each thread prefetches xw for its "own" column (== tid), coalesced
  float xwv = (float)xwb[tid];
  for (int t = 0; t < T_; ++t) {
    float xw_nxt = 0.f;
    if (t + 1 < T_) xw_nxt = (float)xwb[(t + 1) * 1024 + tid];

    float zA0 = (kh == 0) ? xwv : 0.f, zA1 = 0.f;  // col n2
    float zB0 = (kh == 0) ? 0.f : xwv, zB1 = 0.f;  // col n2+512
#pragma unroll
    for (int j = 0; j < LG2; ++j) {
      // issue this sub-iteration's u-LDS loads early; ~24 fdot2 of cover
      uint4 uA = u4[(j * 2 + kh) * 1024 + n2];
      uint4 uB = u4[(j * 2 + kh) * 1024 + n2 + 512];
#pragma unroll
      for (int gg = 0; gg < 3; ++gg) {  // register part: pairs 4g..4g+3
        int g = j * 3 + gg;
        uint4 hh = h4[kh * 16 + g];
        zA0 = fdot2(hh.x, urA[4 * g + 0], zA0);
        zA1 = fdot2(hh.y, urA[4 * g + 1], zA1);
        zA0 = fdot2(hh.z, urA[4 * g + 2], zA0);
        zA1 = fdot2(hh.w, urA[4 * g + 3], zA1);
        zB0 = fdot2(hh.x, urB[4 * g + 0], zB0);
        zB1 = fdot2(hh.y, urB[4 * g + 1], zB1);
        zB0 = fdot2(hh.z, urB[4 * g + 2], zB0);
        zB1 = fdot2(hh.w, urB[4 * g + 3], zB1);
      }
      {  // consume LDS group j (h pairs RP2+4j .. +3)
        uint4 hh = h4[kh * 16 + RP2 / 4 + j];
        zA0 = fdot2(hh.x, uA.x, zA0);
        zA1 = fdot2(hh.y, uA.y, zA1);
        zA0 = fdot2(hh.z, uA.z, zA0);
        zA1 = fdot2(hh.w, uA.w, zA1);
        zB0 = fdot2(hh.x, uB.x, zB0);
        zB1 = fdot2(hh.y, uB.y, zB1);
        zB0 = fdot2(hh.z, uB.z, zB0);
        zB1 = fdot2(hh.w, uB.w, zB1);
      }
    }
    z_lds[kh * 1024 + n2] = zA0 + zA1;
    z_lds[kh * 1024 + n2 + 512] = zB0 + zB1;
    __syncthreads();
    if (tid < 256) {
      float zi = z_lds[tid] + z_lds[1024 + tid];
      float zf = z_lds[256 + tid] + z_lds[1280 + tid];
      float zg = z_lds[512 + tid] + z_lds[1536 + tid];
      float zo = z_lds[768 + tid] + z_lds[1792 + tid];
      float ig = 1.f / (1.f + __expf(-zi));
      float fg = 1.f / (1.f + __expf(-zf));
      float gg = 1.f - 2.f / (1.f + __expf(2.f * zg));
      float og = 1.f / (1.f + __expf(-zo));
      c_st = fg * c_st + ig * gg;
      float hv = og * (1.f - 2.f / (1.f + __expf(2.f * c_st)));
      encb[t * 256 + tid] = hv;
      h_lds[tid] = (f16)hv;
    }
    __syncthreads();
    xwv = xw_nxt;
  }
}

extern "C" void kernel_launch(void* const* d_in, const int* in_sizes, int n_in,
                              void* d_out, int out_size, void* d_ws, size_t ws_size,
                              hipStream_t stream) {
  const float* X = (const float*)d_in[0];
  const float* Wa = (const float*)d_in[1];
  const float* Wl = (const float*)d_in[3];
  const float* Ul = (const float*)d_in[4];
  const float* bl = (const float*)d_in[5];
  float* out = (float*)d_out;
  uint8_t* ws = (uint8_t*)d_ws;

  float* alpha = (float*)ws;                          // 131072 B
  uint32_t* u_packed = (uint32_t*)(ws + 131072);      // 524288 B
  f16* wt = (f16*)(ws + 655360);                      // 524288 B
  f16* xw = (f16*)(ws + 1179648);                     // 66846720 B (~68 MB total)

  k0_pack<<<1024, 256, 0, stream>>>(Wl, Ul, u_packed, wt);
  k1_alpha<<<128, 256, 0, stream>>>(X, Wa, alpha);
  k2_xtilde<<<8160, 256, 0, stream>>>((const float4*)X, alpha, (float4*)out);
  dim3 g3(255, 8);
  k3_gemm<<<g3, 256, 0, stream>>>(out, wt, bl, xw);
  k4_recur<<<128, 1024, 0, stream>>>(X, u_packed, xw, out + 8355840);
}